// Round 1
// 441.756 us; speedup vs baseline: 1.0657x; 1.0657x over previous
//
#include <hip/hip_runtime.h>
#include <cmath>

#define NN 100000
#define EE 400000
#define ET (EE + NN)          // 500000 edges incl. self-loops
#define SLOPE 0.2f

typedef __attribute__((ext_vector_type(8))) short short8;
typedef __attribute__((ext_vector_type(4))) float floatx4;

__device__ __forceinline__ float b2f(ushort u) {
    union { unsigned int i; float f; } v; v.i = ((unsigned int)u) << 16; return v.f;
}
__device__ __forceinline__ float bl(uint u) {   // low bf16 of packed uint -> f32
    union { unsigned int i; float f; } v; v.i = u << 16; return v.f;
}
__device__ __forceinline__ float bh(uint u) {   // high bf16 of packed uint -> f32
    union { unsigned int i; float f; } v; v.i = u & 0xffff0000u; return v.f;
}
__device__ __forceinline__ ushort f2b(float f) {
    union { float f; unsigned int i; } v; v.f = f;
    unsigned int r = v.i + 0x7FFFu + ((v.i >> 16) & 1u);   // RNE
    return (ushort)(r >> 16);
}

// ---------------------------------------------------------------- CSR build
__global__ __launch_bounds__(256) void count_deg(const int* __restrict__ ei, int* __restrict__ deg) {
    int e = blockIdx.x * 256 + threadIdx.x;
    if (e < EE) atomicAdd(&deg[ei[EE + e]], 1);
}

__global__ __launch_bounds__(256) void scan1(const int* __restrict__ deg, int* __restrict__ incl,
                                             int* __restrict__ bsums) {
    __shared__ int ts[256];
    int b = blockIdx.x, t = threadIdx.x;
    int base = b * 1024 + t * 4;
    int v[4];
#pragma unroll
    for (int i = 0; i < 4; i++) {
        int n = base + i;
        v[i] = (n < NN) ? (deg[n] + 1) : 0;
    }
    int s = 0;
#pragma unroll
    for (int i = 0; i < 4; i++) { s += v[i]; v[i] = s; }
    ts[t] = s;
    __syncthreads();
    for (int off = 1; off < 256; off <<= 1) {
        int x = (t >= off) ? ts[t - off] : 0;
        __syncthreads();
        ts[t] += x;
        __syncthreads();
    }
    int excl = ts[t] - s;
#pragma unroll
    for (int i = 0; i < 4; i++) {
        int n = base + i;
        if (n < NN) incl[n] = v[i] + excl;
    }
    if (t == 255) bsums[b] = ts[255];
}

__global__ __launch_bounds__(128) void scan2(int* __restrict__ bsums, int nblk) {
    __shared__ int ts[128];
    int t = threadIdx.x;
    int v = (t < nblk) ? bsums[t] : 0;
    ts[t] = v;
    __syncthreads();
    for (int off = 1; off < 128; off <<= 1) {
        int x = (t >= off) ? ts[t - off] : 0;
        __syncthreads();
        ts[t] += x;
        __syncthreads();
    }
    if (t < nblk) bsums[t] = ts[t] - v;
}

__global__ __launch_bounds__(256) void scan3(const int* __restrict__ incl, const int* __restrict__ deg,
                                             const int* __restrict__ bsums, int* __restrict__ row_ptr,
                                             int* __restrict__ cursor) {
    int n = blockIdx.x * 256 + threadIdx.x;
    if (n < NN) {
        int rp = incl[n] - (deg[n] + 1) + bsums[n >> 10];
        row_ptr[n] = rp;
        cursor[n] = rp;
    }
    if (n == 0) row_ptr[NN] = ET;
}

__global__ __launch_bounds__(256) void scatter(const int* __restrict__ ei, int* __restrict__ cursor,
                                               int* __restrict__ col) {
    int e = blockIdx.x * 256 + threadIdx.x;
    if (e < EE) {
        int d = ei[EE + e];
        int p = atomicAdd(&cursor[d], 1);
        col[p] = ei[e];
    }
}

__global__ __launch_bounds__(256) void selfloop(const int* __restrict__ cursor, int* __restrict__ col) {
    int n = blockIdx.x * 256 + threadIdx.x;
    if (n < NN) col[cursor[n]] = n;
}

// ---------------------------------------------------------------- casts
__global__ __launch_bounds__(256) void cast_to_bf16(const float* __restrict__ in,
                                                    ushort* __restrict__ out, int n4) {
    int i = blockIdx.x * 256 + threadIdx.x;
    if (i < n4) {
        float4 v = ((const float4*)in)[i];
        ushort4 o;
        o.x = f2b(v.x); o.y = f2b(v.y); o.z = f2b(v.z); o.w = f2b(v.w);
        ((ushort4*)out)[i] = o;
    }
}

// all three weight transposes in one launch: Wt[n*K + k] = bf16(W[k*N + n])
__global__ __launch_bounds__(256) void transpose_cast_all(const float* __restrict__ W0,
                                                          const float* __restrict__ W1,
                                                          const float* __restrict__ W2,
                                                          ushort* __restrict__ Wt0,
                                                          ushort* __restrict__ Wt1,
                                                          ushort* __restrict__ Wt2) {
    int idx = blockIdx.x * 256 + threadIdx.x;
    if (idx < 32768) {                       // W0: K=128, N=256
        int n = idx >> 7, k = idx & 127;
        Wt0[idx] = f2b(W0[(size_t)k * 256 + n]);
    } else if (idx < 32768 + 65536) {        // W1: K=256, N=256
        int j = idx - 32768;
        int n = j >> 8, k = j & 255;
        Wt1[j] = f2b(W1[(size_t)k * 256 + n]);
    } else if (idx < 131072) {               // W2: K=256, N=128
        int j = idx - 98304;
        int n = j >> 8, k = j & 255;
        Wt2[j] = f2b(W2[(size_t)k * 128 + n]);
    }
}

// ---------------------------------------------------------------- bf16 MFMA GEMM + fused scores
// C[M,N] bf16 = A[M,K] bf16 @ Bt[N,K]^T bf16, fp32 accum
// tile 128x128, BK=32, 256 threads = 4 waves (2x2), wave computes 64x64
// Epilogue also computes als/ald = (C-row . a_src/a_dst per head) from the live
// accumulators: a wave's 64 cols == one head for C=64 (direct store); for C=128
// (layer 2) two waves share a head -> atomicAdd into pre-zeroed buffers.
#define LP 40   // LDS row pitch in bf16 elems (80 B, 16B-aligned)
__global__ __launch_bounds__(256) void gemm_bf16(const ushort* __restrict__ A,
                                                 const ushort* __restrict__ Bt,
                                                 ushort* __restrict__ C,
                                                 int M, int K, int N,
                                                 const float* __restrict__ asf,
                                                 const float* __restrict__ adf,
                                                 float* __restrict__ als,
                                                 float* __restrict__ ald,
                                                 int H, int lgC) {
    __shared__ ushort As[128 * LP];
    __shared__ ushort Bs[128 * LP];
    int tid = threadIdx.x;
    int bm = blockIdx.x * 128;
    int bn = blockIdx.y * 128;
    int wave = tid >> 6, lane = tid & 63;
    int wm = (wave >> 1) * 64, wn = (wave & 1) * 64;

    floatx4 acc[4][4];
#pragma unroll
    for (int i = 0; i < 4; i++)
#pragma unroll
        for (int j = 0; j < 4; j++) acc[i][j] = (floatx4)0.f;

    int r = tid >> 1;            // staging row 0..127
    int c = (tid & 1) * 16;      // col half: 0 or 16

    int frow = lane & 15;
    int kq = (lane >> 4) * 8;

    for (int k0 = 0; k0 < K; k0 += 32) {
        uint4 a0, a1;
        if (bm + r < M) {
            const uint4* ap = (const uint4*)(A + (size_t)(bm + r) * K + k0 + c);
            a0 = ap[0]; a1 = ap[1];
        } else {
            a0 = make_uint4(0, 0, 0, 0); a1 = a0;
        }
        *(uint4*)&As[r * LP + c]     = a0;
        *(uint4*)&As[r * LP + c + 8] = a1;

        const uint4* bp = (const uint4*)(Bt + (size_t)(bn + r) * K + k0 + c);
        *(uint4*)&Bs[r * LP + c]     = bp[0];
        *(uint4*)&Bs[r * LP + c + 8] = bp[1];

        __syncthreads();

        short8 afr[4], bfr[4];
#pragma unroll
        for (int i = 0; i < 4; i++)
            afr[i] = *(const short8*)&As[(wm + i * 16 + frow) * LP + kq];
#pragma unroll
        for (int j = 0; j < 4; j++)
            bfr[j] = *(const short8*)&Bs[(wn + j * 16 + frow) * LP + kq];
#pragma unroll
        for (int i = 0; i < 4; i++)
#pragma unroll
            for (int j = 0; j < 4; j++)
                acc[i][j] = __builtin_amdgcn_mfma_f32_16x16x32_bf16(afr[i], bfr[j], acc[i][j], 0, 0, 0);

        __syncthreads();
    }

    int ccol = bn + wn + (lane & 15);
    int crow = bm + wm + (lane >> 4) * 4;
#pragma unroll
    for (int i = 0; i < 4; i++) {
#pragma unroll
        for (int reg = 0; reg < 4; reg++) {
            int row = crow + i * 16 + reg;
            if (row < M) {
#pragma unroll
                for (int j = 0; j < 4; j++)
                    C[(size_t)row * N + ccol + j * 16] = f2b(acc[i][j][reg]);
            }
        }
    }

    // ---- fused attention scores (als/ald per node & head)
    {
        int cb = bn + wn + (lane & 15);
        float asv[4], adv[4];
#pragma unroll
        for (int j = 0; j < 4; j++) {
            asv[j] = asf[cb + j * 16];
            adv[j] = adf[cb + j * 16];
        }
        int hidx = (bn + wn) >> lgC;
#pragma unroll
        for (int i = 0; i < 4; i++) {
#pragma unroll
            for (int reg = 0; reg < 4; reg++) {
                float ss = acc[i][0][reg] * asv[0] + acc[i][1][reg] * asv[1]
                         + acc[i][2][reg] * asv[2] + acc[i][3][reg] * asv[3];
                float dd = acc[i][0][reg] * adv[0] + acc[i][1][reg] * adv[1]
                         + acc[i][2][reg] * adv[2] + acc[i][3][reg] * adv[3];
#pragma unroll
                for (int off = 1; off < 16; off <<= 1) {
                    ss += __shfl_xor(ss, off, 64);
                    dd += __shfl_xor(dd, off, 64);
                }
                int row = crow + i * 16 + reg;
                if ((lane & 15) == 0 && row < M) {
                    if (lgC == 6) {           // one head fully inside this wave
                        als[row * H + hidx] = ss;
                        ald[row * H + hidx] = dd;
                    } else {                  // head spans two waves (layer 2)
                        atomicAdd(&als[row], ss);
                        atomicAdd(&ald[row], dd);
                    }
                }
            }
        }
    }
}

// ---------------------------------------------------------------- CSR aggregation v4
// TWO DST NODES PER WAVE (half-wave = 32 lanes each). Fixed per-dst cost
// (softmax shuffles, setup, epilogue) shared by 2 dsts; gather loads are
// dwordx4 for HC=256. Fast path: deg <= GS (GS = 32/H edge slots per head).
template <int H, int HC, bool ELU_ACT, bool OUT_BF16>
__global__ __launch_bounds__(256) void aggregate2(const ushort* __restrict__ hlin,
                                                  const float* __restrict__ als,
                                                  const float* __restrict__ ald,
                                                  const int* __restrict__ row_ptr,
                                                  const int* __restrict__ col,
                                                  const float* __restrict__ bias,
                                                  void* __restrict__ outv) {
    constexpr int CP = HC / 32;       // channels per lane (8 or 4)
    constexpr int GS = 32 / H;        // edge slots per head (8 or 32)
    constexpr int NU = CP / 2;        // packed uints per lane per edge (4 or 2)
    int wv = threadIdx.x >> 6, lane = threadIdx.x & 63;
    int hl = lane & 31;
    int dst = blockIdx.x * 8 + wv * 2 + (lane >> 5);   // NN == 8*12500, no guard needed
    int rs = row_ptr[dst];
    int deg = row_ptr[dst + 1] - rs;
    int eg = hl & (GS - 1);
    int head = hl / GS;
    float ad = ald[dst * H + head];
    uint uoff = (uint)hl * NU;        // uint offset into a node's channel row

    float acc[CP];
#pragma unroll
    for (int j = 0; j < CP; j++) acc[j] = 0.f;

    int degB = __shfl_xor(deg, 32, 64);   // other half's degree (all lanes active)

    if (deg <= GS) {
        // ---- fast path: slot eg owns edge eg (94.9% of nodes for H=4)
        int src = 0;
        float s = -1e30f;
        if (eg < deg) {
            src = col[rs + eg];
            float sc = als[src * H + head] + ad;
            s = sc > 0.f ? sc : SLOPE * sc;
        }
        float m = s;
#pragma unroll
        for (int off = 1; off < GS; off <<= 1) m = fmaxf(m, __shfl_xor(m, off, 64));
        float e = (eg < deg) ? __expf(s - m) : 0.f;
        float sum = e;
#pragma unroll
        for (int off = 1; off < GS; off <<= 1) sum += __shfl_xor(sum, off, 64);
        float w = e * (1.0f / (sum + 1e-16f));

        // lockstep only with the other half if it is also on the fast path
        int mdeg = max(deg, (degB <= GS) ? degB : 0);
        int sbase = lane & 32;                        // head-0 slot base of my half
        int wbase = (lane & 32) | (hl & ~(GS - 1));   // my head's slot base

        for (int d = 0; d < mdeg; d += 4) {
            int s0 = __shfl(src, sbase + d, 64);
            int s1 = __shfl(src, sbase + d + 1, 64);
            int s2 = __shfl(src, sbase + d + 2, 64);
            int s3 = __shfl(src, sbase + d + 3, 64);
            float w0 = __shfl(w, wbase + d, 64);
            float w1 = __shfl(w, wbase + d + 1, 64);
            float w2 = __shfl(w, wbase + d + 2, 64);
            float w3 = __shfl(w, wbase + d + 3, 64);
            const uint* p0 = (const uint*)(hlin + (size_t)s0 * HC) + uoff;
            const uint* p1 = (const uint*)(hlin + (size_t)s1 * HC) + uoff;
            const uint* p2 = (const uint*)(hlin + (size_t)s2 * HC) + uoff;
            const uint* p3 = (const uint*)(hlin + (size_t)s3 * HC) + uoff;
            uint u0[NU], u1[NU], u2[NU], u3[NU];
#pragma unroll
            for (int q = 0; q < NU; q++) { u0[q] = p0[q]; u1[q] = p1[q]; u2[q] = p2[q]; u3[q] = p3[q]; }
#pragma unroll
            for (int q = 0; q < NU; q++) {
                acc[2*q]   += w0 * bl(u0[q]) + w1 * bl(u1[q]) + w2 * bl(u2[q]) + w3 * bl(u3[q]);
                acc[2*q+1] += w0 * bh(u0[q]) + w1 * bh(u1[q]) + w2 * bh(u2[q]) + w3 * bh(u3[q]);
            }
        }
    } else {
        // ---- rare long-row path (strided over GS slots within the half)
        float m = -1e30f;
        for (int e2 = eg; e2 < deg; e2 += GS) {
            int s0 = col[rs + e2];
            float sc = als[s0 * H + head] + ad;
            sc = sc > 0.f ? sc : SLOPE * sc;
            m = fmaxf(m, sc);
        }
#pragma unroll
        for (int off = 1; off < GS; off <<= 1) m = fmaxf(m, __shfl_xor(m, off, 64));
        float sum = 0.f;
        for (int e2 = eg; e2 < deg; e2 += GS) {
            int s0 = col[rs + e2];
            float sc = als[s0 * H + head] + ad;
            sc = sc > 0.f ? sc : SLOPE * sc;
            sum += __expf(sc - m);
        }
#pragma unroll
        for (int off = 1; off < GS; off <<= 1) sum += __shfl_xor(sum, off, 64);
        float inv = 1.0f / (sum + 1e-16f);
        for (int d = 0; d < deg; d++) {
            int sd = col[rs + d];                 // uniform per half
            float sc = als[sd * H + head] + ad;
            sc = sc > 0.f ? sc : SLOPE * sc;
            float wd = __expf(sc - m) * inv;
            const uint* p = (const uint*)(hlin + (size_t)sd * HC) + uoff;
#pragma unroll
            for (int q = 0; q < NU; q++) {
                uint u = p[q];
                acc[2*q]   += wd * bl(u);
                acc[2*q+1] += wd * bh(u);
            }
        }
    }

    // epilogue: bias (+ ELU) and store
#pragma unroll
    for (int j = 0; j < CP; j++) {
        float v = acc[j] + bias[hl * CP + j];
        if (ELU_ACT) v = v > 0.f ? v : (__expf(v) - 1.0f);
        acc[j] = v;
    }
    if (OUT_BF16) {
        uint* outp = (uint*)((ushort*)outv + (size_t)dst * HC) + uoff;
        uint pk[NU];
#pragma unroll
        for (int q = 0; q < NU; q++)
            pk[q] = (uint)f2b(acc[2*q]) | ((uint)f2b(acc[2*q+1]) << 16);
#pragma unroll
        for (int q = 0; q < NU; q++) outp[q] = pk[q];
    } else {
        float* outp = (float*)outv + (size_t)dst * HC + hl * CP;
#pragma unroll
        for (int j = 0; j < CP; j++) outp[j] = acc[j];
    }
}

// ---------------------------------------------------------------- launch
extern "C" void kernel_launch(void* const* d_in, const int* in_sizes, int n_in,
                              void* d_out, int out_size, void* d_ws, size_t ws_size,
                              hipStream_t stream) {
    const float* x   = (const float*)d_in[0];
    const int*   ei  = (const int*)d_in[1];
    const float* W0  = (const float*)d_in[2];
    const float* as0 = (const float*)d_in[3];
    const float* ad0 = (const float*)d_in[4];
    const float* b0  = (const float*)d_in[5];
    const float* W1  = (const float*)d_in[6];
    const float* as1 = (const float*)d_in[7];
    const float* ad1 = (const float*)d_in[8];
    const float* b1  = (const float*)d_in[9];
    const float* W2  = (const float*)d_in[10];
    const float* as2 = (const float*)d_in[11];
    const float* ad2 = (const float*)d_in[12];
    const float* b2  = (const float*)d_in[13];
    float* out = (float*)d_out;

    char* ws = (char*)d_ws;
    size_t off = 0;
    auto alloc = [&](size_t bytes) {
        void* p = ws + off;
        off += (bytes + 255) & ~(size_t)255;
        return p;
    };
    ushort* xb   = (ushort*)alloc((size_t)NN * 128 * 2);
    ushort* h    = (ushort*)alloc((size_t)NN * 256 * 2);
    ushort* actB = (ushort*)alloc((size_t)NN * 256 * 2);
    ushort* actC = (ushort*)alloc((size_t)NN * 256 * 2);
    ushort* Wt0  = (ushort*)alloc((size_t)256 * 128 * 2);
    ushort* Wt1  = (ushort*)alloc((size_t)256 * 256 * 2);
    ushort* Wt2  = (ushort*)alloc((size_t)128 * 256 * 2);
    float* als   = (float*)alloc((size_t)NN * 4 * 4);
    float* ald   = (float*)alloc((size_t)NN * 4 * 4);
    int* deg     = (int*)alloc((size_t)NN * 4);
    int* incl    = (int*)alloc((size_t)NN * 4);
    int* row_ptr = (int*)alloc((size_t)(NN + 1) * 4);
    int* cursor  = (int*)alloc((size_t)NN * 4);
    int* col     = (int*)alloc((size_t)ET * 4);
    int* bsums   = (int*)alloc(128 * 4);

    const int NBLK = (NN + 1023) / 1024;   // 98

    // ---- CSR (shared by all layers)
    hipMemsetAsync(deg, 0, (size_t)NN * 4, stream);
    count_deg<<<(EE + 255) / 256, 256, 0, stream>>>(ei, deg);
    scan1<<<NBLK, 256, 0, stream>>>(deg, incl, bsums);
    scan2<<<1, 128, 0, stream>>>(bsums, NBLK);
    scan3<<<(NN + 255) / 256, 256, 0, stream>>>(incl, deg, bsums, row_ptr, cursor);
    scatter<<<(EE + 255) / 256, 256, 0, stream>>>(ei, cursor, col);
    selfloop<<<(NN + 255) / 256, 256, 0, stream>>>(cursor, col);

    // ---- bf16 conversions
    cast_to_bf16<<<(NN * 128 / 4 + 255) / 256, 256, 0, stream>>>(x, xb, NN * 128 / 4);
    transpose_cast_all<<<(131072 + 255) / 256, 256, 0, stream>>>(W0, W1, W2, Wt0, Wt1, Wt2);

    const int GM = (NN + 127) / 128;   // 782
    const int NB8 = NN / 8;            // 12500 (exact)

    // ---- layer 0 (scores fused into GEMM epilogue)
    gemm_bf16<<<dim3(GM, 2), 256, 0, stream>>>(xb, Wt0, h, NN, 128, 256, as0, ad0, als, ald, 4, 6);
    aggregate2<4, 256, true, true><<<NB8, 256, 0, stream>>>(h, als, ald, row_ptr, col, b0, actB);

    // ---- layer 1
    gemm_bf16<<<dim3(GM, 2), 256, 0, stream>>>(actB, Wt1, h, NN, 256, 256, as1, ad1, als, ald, 4, 6);
    aggregate2<4, 256, true, true><<<NB8, 256, 0, stream>>>(h, als, ald, row_ptr, col, b1, actC);

    // ---- layer 2 (H=1, C=128: head spans two waves -> atomic accumulate)
    hipMemsetAsync(als, 0, (size_t)NN * 4, stream);
    hipMemsetAsync(ald, 0, (size_t)NN * 4, stream);
    gemm_bf16<<<dim3(GM, 1), 256, 0, stream>>>(actC, Wt2, h, NN, 256, 128, as2, ad2, als, ald, 1, 7);
    aggregate2<1, 128, false, false><<<NB8, 256, 0, stream>>>(h, als, ald, row_ptr, col, b2, out);
}